// Round 1
// baseline (541.936 us; speedup 1.0000x reference)
//
#include <hip/hip_runtime.h>
#include <math.h>

#define S_LEN 4096
#define F_DIM 512
#define NSPLIT 4
#define KSPLIT (S_LEN / NSPLIT)

typedef __attribute__((ext_vector_type(8))) short bf16x8;
typedef __attribute__((ext_vector_type(4))) float f32x4;

__device__ __forceinline__ unsigned short f2bf(float x) {
    union { float f; unsigned u; } v; v.f = x;
    unsigned r = v.u + 0x7fffu + ((v.u >> 16) & 1u);
    return (unsigned short)(r >> 16);
}
__device__ __forceinline__ float bf2f(unsigned short b) {
    union { unsigned u; float f; } v; v.u = ((unsigned)b) << 16;
    return v.f;
}

// ---------------- fp32 -> bf16 cast (vectorized) ----------------
__global__ void cast_f32_bf16(const float* __restrict__ src,
                              unsigned short* __restrict__ dst, int n4) {
    int i = blockIdx.x * blockDim.x + threadIdx.x;
    if (i >= n4) return;
    float4 v = ((const float4*)src)[i];
    ushort4 o;
    o.x = f2bf(v.x); o.y = f2bf(v.y); o.z = f2bf(v.z); o.w = f2bf(v.w);
    ((ushort4*)dst)[i] = o;
}

// ---------------- projection GEMM: out = op(X @ W^T + b) ----------------
// X: M x K (bf16 row-major), W: N x K (bf16 row-major)  -> "NT" gemm, MFMA-friendly
// 64x64 tile, BK=32, 256 threads = 4 waves; wave w owns rows [16w,16w+16)
__launch_bounds__(256, 2)
__global__ void proj_gemm(const unsigned short* __restrict__ X,
                          const unsigned short* __restrict__ W,
                          const float* __restrict__ bias,
                          unsigned short* __restrict__ out_bf,
                          float* __restrict__ out_f32,
                          int relu) {
    __shared__ __align__(16) unsigned short As[64][48];  // +16 pad: 96B stride, 16B aligned
    __shared__ __align__(16) unsigned short Bs[64][48];
    const int tid = threadIdx.x;
    const int w = tid >> 6, l = tid & 63, quad = l >> 4, ln = l & 15;
    const int m0 = blockIdx.x * 64;
    const int n0 = blockIdx.y * 64;

    f32x4 acc[4];
    f32x4 zero = {0.f, 0.f, 0.f, 0.f};
#pragma unroll
    for (int i = 0; i < 4; ++i) acc[i] = zero;

    const int sr = tid >> 2;        // staging row 0..63
    const int sc = (tid & 3) * 8;   // staging col 0..24

    for (int k0 = 0; k0 < F_DIM; k0 += 32) {
        __syncthreads();
        *(uint4*)&As[sr][sc] = *(const uint4*)(X + (size_t)(m0 + sr) * F_DIM + k0 + sc);
        *(uint4*)&Bs[sr][sc] = *(const uint4*)(W + (size_t)(n0 + sr) * F_DIM + k0 + sc);
        __syncthreads();
        bf16x8 a = *(const bf16x8*)&As[w * 16 + ln][quad * 8];
#pragma unroll
        for (int nt = 0; nt < 4; ++nt) {
            bf16x8 b = *(const bf16x8*)&Bs[nt * 16 + ln][quad * 8];
            acc[nt] = __builtin_amdgcn_mfma_f32_16x16x32_bf16(a, b, acc[nt], 0, 0, 0);
        }
    }

#pragma unroll
    for (int nt = 0; nt < 4; ++nt) {
#pragma unroll
        for (int r = 0; r < 4; ++r) {
            int row = m0 + w * 16 + quad * 4 + r;   // C/D: row = quad*4 + reg
            int col = n0 + nt * 16 + ln;            //      col = lane & 15
            float vv = acc[nt][r] + bias[col];
            if (relu) vv = fmaxf(vv, 0.f);
            size_t off = (size_t)row * F_DIM + col;
            if (out_bf)  out_bf[off] = f2bf(vv);
            if (out_f32) out_f32[off] = vv;
        }
    }
}

// ---------------- q_att[s] = sum_f qq[s][f]*qk[s][f] (one wave per row) ----------------
__global__ void qatt_kernel(const unsigned short* __restrict__ qq,
                            const unsigned short* __restrict__ qk,
                            float* __restrict__ q_att) {
    int w = threadIdx.x >> 6, l = threadIdx.x & 63;
    int row = blockIdx.x * 4 + w;
    uint4 av = *(const uint4*)(qq + (size_t)row * F_DIM + l * 8);
    uint4 bv = *(const uint4*)(qk + (size_t)row * F_DIM + l * 8);
    const unsigned short* ae = (const unsigned short*)&av;
    const unsigned short* be = (const unsigned short*)&bv;
    float s = 0.f;
#pragma unroll
    for (int i = 0; i < 8; ++i) s += bf2f(ae[i]) * bf2f(be[i]);
#pragma unroll
    for (int off = 32; off >= 1; off >>= 1) s += __shfl_xor(s, off);
    if (l == 0) q_att[row] = s;
}

// ---------------- flash attention, split-K partials ----------------
// grid (S/64 row-blocks, NSPLIT). 4 waves/block, wave handles 16 Q rows, full F=512.
__launch_bounds__(256, 1)
__global__ void flash_attn(const unsigned short* __restrict__ qq,
                           const unsigned short* __restrict__ kk,
                           const unsigned short* __restrict__ vv,
                           float* __restrict__ O_part,   // [NSPLIT][S][F]
                           float* __restrict__ m_part,   // [NSPLIT][S]
                           float* __restrict__ l_part) { // [NSPLIT][S]
    // shared buffer reused: K view 32x528 (33.8KB) then V^T view 512x48 (48KB)
    __shared__ __align__(16) unsigned short smbuf[F_DIM * 48];
    __shared__ __align__(16) unsigned short Ps[4][16][32];
    const float scale = 0.04415108f;  // 1/sqrt(513)
    const int tid = threadIdx.x;
    const int w = tid >> 6, l = tid & 63, quad = l >> 4, ln = l & 15;
    const int m0 = blockIdx.x * 64 + w * 16;
    const int j_begin = blockIdx.y * KSPLIT;

    typedef unsigned short (*KsT)[528];
    typedef unsigned short (*VTsT)[48];
    KsT Ks = (KsT)smbuf;
    VTsT VTs = (VTsT)smbuf;

    // preload this wave's 16 Q rows as A-fragments (16 k-chunks of 32)
    bf16x8 aq[16];
    {
        const unsigned short* qrow = qq + (size_t)(m0 + ln) * F_DIM;
#pragma unroll
        for (int kc = 0; kc < 16; ++kc)
            aq[kc] = *(const bf16x8*)(qrow + kc * 32 + quad * 8);
    }
    f32x4 o[32];
    f32x4 zero = {0.f, 0.f, 0.f, 0.f};
#pragma unroll
    for (int i = 0; i < 32; ++i) o[i] = zero;
    float mrun[4] = {-1e30f, -1e30f, -1e30f, -1e30f};
    float lrun[4] = {0.f, 0.f, 0.f, 0.f};

    for (int jj = 0; jj < KSPLIT; jj += 32) {
        const int j0 = j_begin + jj;
        __syncthreads();  // prev PV (reads VTs) done before overwrite
        // stage K rows [j0, j0+32) x 512
#pragma unroll
        for (int it = 0; it < 8; ++it) {
            int idx = it * 2048 + tid * 8;
            int r = idx >> 9, c = idx & 511;
            *(uint4*)&Ks[r][c] = *(const uint4*)(kk + (size_t)(j0 + r) * F_DIM + c);
        }
        __syncthreads();

        // S_tile = qq(16x512) @ kk_tile^T  -> 16x32
        f32x4 sfr0 = zero, sfr1 = zero;
#pragma unroll
        for (int kc = 0; kc < 16; ++kc) {
            bf16x8 b0 = *(const bf16x8*)&Ks[ln][kc * 32 + quad * 8];
            bf16x8 b1 = *(const bf16x8*)&Ks[16 + ln][kc * 32 + quad * 8];
            sfr0 = __builtin_amdgcn_mfma_f32_16x16x32_bf16(aq[kc], b0, sfr0, 0, 0, 0);
            sfr1 = __builtin_amdgcn_mfma_f32_16x16x32_bf16(aq[kc], b1, sfr1, 0, 0, 0);
        }

        // online softmax (rows live in C-layout: row = quad*4+r, col = ln)
        float alpha[4];
#pragma unroll
        for (int r = 0; r < 4; ++r) {
            float v = fmaxf(sfr0[r], sfr1[r]);
#pragma unroll
            for (int off = 8; off >= 1; off >>= 1) v = fmaxf(v, __shfl_xor(v, off));
            float mn = fmaxf(mrun[r], v * scale);
            alpha[r] = expf(mrun[r] - mn);
            mrun[r] = mn;
        }
        float ps0[4], ps1[4];
#pragma unroll
        for (int r = 0; r < 4; ++r) {
            ps0[r] = expf(sfr0[r] * scale - mrun[r]);
            ps1[r] = expf(sfr1[r] * scale - mrun[r]);
            Ps[w][quad * 4 + r][ln]      = f2bf(ps0[r]);
            Ps[w][quad * 4 + r][16 + ln] = f2bf(ps1[r]);
        }
#pragma unroll
        for (int r = 0; r < 4; ++r) {
            float v = ps0[r] + ps1[r];
#pragma unroll
            for (int off = 8; off >= 1; off >>= 1) v += __shfl_xor(v, off);
            lrun[r] = lrun[r] * alpha[r] + v;
        }
#pragma unroll
        for (int i = 0; i < 32; ++i) {
#pragma unroll
            for (int r = 0; r < 4; ++r) o[i][r] *= alpha[r];
        }
        __syncthreads();  // K reads done, Ps visible; now overwrite smbuf with V^T

        // stage V transposed: VTs[f][k_local]
#pragma unroll
        for (int it = 0; it < 8; ++it) {
            int idx = it * 2048 + tid * 8;
            int r = idx >> 9, c = idx & 511;
            uint4 d = *(const uint4*)(vv + (size_t)(j0 + r) * F_DIM + c);
            const unsigned short* e = (const unsigned short*)&d;
#pragma unroll
            for (int i2 = 0; i2 < 8; ++i2) VTs[c + i2][r] = e[i2];
        }
        __syncthreads();

        // O += P(16x32) @ V_tile(32x512)
        bf16x8 pa = *(const bf16x8*)&Ps[w][ln][quad * 8];
#pragma unroll
        for (int nt = 0; nt < 32; ++nt) {
            bf16x8 b = *(const bf16x8*)&VTs[nt * 16 + ln][quad * 8];
            o[nt] = __builtin_amdgcn_mfma_f32_16x16x32_bf16(pa, b, o[nt], 0, 0, 0);
        }
    }

    float* Op = O_part + ((size_t)blockIdx.y * S_LEN + m0) * F_DIM;
#pragma unroll
    for (int nt = 0; nt < 32; ++nt) {
#pragma unroll
        for (int r = 0; r < 4; ++r)
            Op[(size_t)(quad * 4 + r) * F_DIM + nt * 16 + ln] = o[nt][r];
    }
    if (ln == 0) {
#pragma unroll
        for (int r = 0; r < 4; ++r) {
            m_part[(size_t)blockIdx.y * S_LEN + m0 + quad * 4 + r] = mrun[r];
            l_part[(size_t)blockIdx.y * S_LEN + m0 + quad * 4 + r] = lrun[r];
        }
    }
}

// ---------------- combine splits + extra q_att column + elementwise fusion ----------------
__global__ void combine_kernel(const float* __restrict__ O_part,
                               const float* __restrict__ m_part,
                               const float* __restrict__ l_part,
                               const float* __restrict__ q_att,
                               const unsigned short* __restrict__ qv,
                               unsigned short* __restrict__ res_bf) {
    const float scale = 0.04415108f;
    int row = blockIdx.x;
    int t = threadIdx.x;
    __shared__ float coef[NSPLIT];
    if (t == 0) {
        float qa_sc = q_att[row] * scale;
        float m_fin = qa_sc;
        for (int i = 0; i < NSPLIT; ++i)
            m_fin = fmaxf(m_fin, m_part[(size_t)i * S_LEN + row]);
        float l_fin = expf(qa_sc - m_fin);  // extra column: denominator only
        float c[NSPLIT];
        for (int i = 0; i < NSPLIT; ++i) {
            c[i] = expf(m_part[(size_t)i * S_LEN + row] - m_fin);
            l_fin += l_part[(size_t)i * S_LEN + row] * c[i];
        }
        float inv = 1.f / l_fin;
        for (int i = 0; i < NSPLIT; ++i) coef[i] = c[i] * inv;
    }
    __syncthreads();
    float qa = q_att[row];
    for (int f = t; f < F_DIM; f += blockDim.x) {
        float acc = 0.f;
#pragma unroll
        for (int i = 0; i < NSPLIT; ++i)
            acc += coef[i] * O_part[((size_t)i * S_LEN + row) * F_DIM + f];
        float r = bf2f(qv[(size_t)row * F_DIM + f]) * qa + acc;
        res_bf[(size_t)row * F_DIM + f] = f2bf(r);
    }
}

extern "C" void kernel_launch(void* const* d_in, const int* in_sizes, int n_in,
                              void* d_out, int out_size, void* d_ws, size_t ws_size,
                              hipStream_t stream) {
    const float* q  = (const float*)d_in[0];
    const float* k  = (const float*)d_in[1];
    const float* v  = (const float*)d_in[2];
    const float* Wq = (const float*)d_in[3];
    const float* bq = (const float*)d_in[4];
    const float* Wk = (const float*)d_in[5];
    const float* bk = (const float*)d_in[6];
    const float* Wv = (const float*)d_in[7];
    const float* bv = (const float*)d_in[8];
    const float* Wo = (const float*)d_in[9];
    const float* bo = (const float*)d_in[10];
    float* out = (float*)d_out;

    char* p = (char*)d_ws;
    auto alloc = [&](size_t bytes) -> char* {
        char* r = p; p += (bytes + 255) & ~(size_t)255; return r;
    };
    const size_t SF = (size_t)S_LEN * F_DIM;
    unsigned short* q_bf  = (unsigned short*)alloc(SF * 2);
    unsigned short* k_bf  = (unsigned short*)alloc(SF * 2);
    unsigned short* v_bf  = (unsigned short*)alloc(SF * 2);
    unsigned short* qq_bf = (unsigned short*)alloc(SF * 2);
    unsigned short* kk_bf = (unsigned short*)alloc(SF * 2);
    unsigned short* vv_bf = (unsigned short*)alloc(SF * 2);
    unsigned short* qk_bf = (unsigned short*)alloc(SF * 2);
    unsigned short* qv_bf = (unsigned short*)alloc(SF * 2);
    unsigned short* res_bf = (unsigned short*)alloc(SF * 2);
    unsigned short* wq_bf = (unsigned short*)alloc((size_t)F_DIM * F_DIM * 2);
    unsigned short* wk_bf = (unsigned short*)alloc((size_t)F_DIM * F_DIM * 2);
    unsigned short* wv_bf = (unsigned short*)alloc((size_t)F_DIM * F_DIM * 2);
    unsigned short* wo_bf = (unsigned short*)alloc((size_t)F_DIM * F_DIM * 2);
    float* q_att  = (float*)alloc((size_t)S_LEN * 4);
    float* m_part = (float*)alloc((size_t)NSPLIT * S_LEN * 4);
    float* l_part = (float*)alloc((size_t)NSPLIT * S_LEN * 4);
    float* O_part = (float*)alloc((size_t)NSPLIT * SF * 4);

    int n4 = (int)(SF / 4);
    cast_f32_bf16<<<n4 / 256, 256, 0, stream>>>(q, q_bf, n4);
    cast_f32_bf16<<<n4 / 256, 256, 0, stream>>>(k, k_bf, n4);
    cast_f32_bf16<<<n4 / 256, 256, 0, stream>>>(v, v_bf, n4);
    int w4 = F_DIM * F_DIM / 4;
    cast_f32_bf16<<<w4 / 256, 256, 0, stream>>>(Wq, wq_bf, w4);
    cast_f32_bf16<<<w4 / 256, 256, 0, stream>>>(Wk, wk_bf, w4);
    cast_f32_bf16<<<w4 / 256, 256, 0, stream>>>(Wv, wv_bf, w4);
    cast_f32_bf16<<<w4 / 256, 256, 0, stream>>>(Wo, wo_bf, w4);

    dim3 pgrid(S_LEN / 64, F_DIM / 64);
    proj_gemm<<<pgrid, 256, 0, stream>>>(q_bf, wq_bf, bq, qq_bf, nullptr, 1);
    proj_gemm<<<pgrid, 256, 0, stream>>>(k_bf, wk_bf, bk, kk_bf, nullptr, 1);
    proj_gemm<<<pgrid, 256, 0, stream>>>(v_bf, wv_bf, bv, vv_bf, nullptr, 1);
    proj_gemm<<<pgrid, 256, 0, stream>>>(q_bf, wk_bf, bk, qk_bf, nullptr, 0);
    proj_gemm<<<pgrid, 256, 0, stream>>>(q_bf, wv_bf, bv, qv_bf, nullptr, 0);

    qatt_kernel<<<S_LEN / 4, 256, 0, stream>>>(qq_bf, qk_bf, q_att);

    flash_attn<<<dim3(S_LEN / 64, NSPLIT), 256, 0, stream>>>(qq_bf, kk_bf, vv_bf,
                                                             O_part, m_part, l_part);

    combine_kernel<<<S_LEN, 128, 0, stream>>>(O_part, m_part, l_part, q_att, qv_bf, res_bf);

    proj_gemm<<<pgrid, 256, 0, stream>>>(res_bf, wo_bf, bo, nullptr, out, 1);
}

// Round 2
// 293.651 us; speedup vs baseline: 1.8455x; 1.8455x over previous
//
#include <hip/hip_runtime.h>
#include <math.h>

#define S_LEN 4096
#define F_DIM 512
#define NSPLIT 8
#define KSPLIT (S_LEN / NSPLIT)

typedef __attribute__((ext_vector_type(8))) short bf16x8;
typedef __attribute__((ext_vector_type(4))) float f32x4;

__device__ __forceinline__ unsigned short f2bf(float x) {
    union { float f; unsigned u; } v; v.f = x;
    unsigned r = v.u + 0x7fffu + ((v.u >> 16) & 1u);
    return (unsigned short)(r >> 16);
}
__device__ __forceinline__ float bf2f(unsigned short b) {
    union { unsigned u; float f; } v; v.u = ((unsigned)b) << 16;
    return v.f;
}

// ---------------- fp32 -> bf16 cast (vectorized) ----------------
__global__ void cast_f32_bf16(const float* __restrict__ src,
                              unsigned short* __restrict__ dst, int n4) {
    int i = blockIdx.x * blockDim.x + threadIdx.x;
    if (i >= n4) return;
    float4 v = ((const float4*)src)[i];
    ushort4 o;
    o.x = f2bf(v.x); o.y = f2bf(v.y); o.z = f2bf(v.z); o.w = f2bf(v.w);
    ((ushort4*)dst)[i] = o;
}

// ---------------- bf16 transpose: src [S][F] -> dst [F][S] ----------------
__global__ void transpose_bf16(const unsigned short* __restrict__ src,
                               unsigned short* __restrict__ dst) {
    __shared__ __align__(16) unsigned short tile[64][72];  // 144B row stride
    const int s0 = blockIdx.x * 64, f0 = blockIdx.y * 64;
    const int tid = threadIdx.x;
#pragma unroll
    for (int it = 0; it < 2; ++it) {
        int u = it * 256 + tid;
        int r = u >> 3, c = (u & 7) * 8;
        *(uint4*)&tile[r][c] = *(const uint4*)(src + (size_t)(s0 + r) * F_DIM + f0 + c);
    }
    __syncthreads();
#pragma unroll
    for (int it = 0; it < 2; ++it) {
        int u = it * 256 + tid;
        int fl = u >> 3, sc = (u & 7) * 8;
        unsigned short tmp[8];
#pragma unroll
        for (int i = 0; i < 8; ++i) tmp[i] = tile[sc + i][fl];
        *(uint4*)(dst + (size_t)(f0 + fl) * S_LEN + s0 + sc) = *(uint4*)tmp;
    }
}

// ---------------- projection GEMM: out = op(X @ W^T + b) ----------------
__launch_bounds__(256, 2)
__global__ void proj_gemm(const unsigned short* __restrict__ X,
                          const unsigned short* __restrict__ W,
                          const float* __restrict__ bias,
                          unsigned short* __restrict__ out_bf,
                          float* __restrict__ out_f32,
                          int relu) {
    __shared__ __align__(16) unsigned short As[64][48];
    __shared__ __align__(16) unsigned short Bs[64][48];
    const int tid = threadIdx.x;
    const int w = tid >> 6, l = tid & 63, quad = l >> 4, ln = l & 15;
    const int m0 = blockIdx.x * 64;
    const int n0 = blockIdx.y * 64;

    f32x4 acc[4];
    f32x4 zero = {0.f, 0.f, 0.f, 0.f};
#pragma unroll
    for (int i = 0; i < 4; ++i) acc[i] = zero;

    const int sr = tid >> 2;
    const int sc = (tid & 3) * 8;

    for (int k0 = 0; k0 < F_DIM; k0 += 32) {
        __syncthreads();
        *(uint4*)&As[sr][sc] = *(const uint4*)(X + (size_t)(m0 + sr) * F_DIM + k0 + sc);
        *(uint4*)&Bs[sr][sc] = *(const uint4*)(W + (size_t)(n0 + sr) * F_DIM + k0 + sc);
        __syncthreads();
        bf16x8 a = *(const bf16x8*)&As[w * 16 + ln][quad * 8];
#pragma unroll
        for (int nt = 0; nt < 4; ++nt) {
            bf16x8 b = *(const bf16x8*)&Bs[nt * 16 + ln][quad * 8];
            acc[nt] = __builtin_amdgcn_mfma_f32_16x16x32_bf16(a, b, acc[nt], 0, 0, 0);
        }
    }

#pragma unroll
    for (int nt = 0; nt < 4; ++nt) {
#pragma unroll
        for (int r = 0; r < 4; ++r) {
            int row = m0 + w * 16 + quad * 4 + r;
            int col = n0 + nt * 16 + ln;
            float vv = acc[nt][r] + bias[col];
            if (relu) vv = fmaxf(vv, 0.f);
            size_t off = (size_t)row * F_DIM + col;
            if (out_bf)  out_bf[off] = f2bf(vv);
            if (out_f32) out_f32[off] = vv;
        }
    }
}

// ---------------- q_att[s] = sum_f qq[s][f]*qk[s][f] ----------------
__global__ void qatt_kernel(const unsigned short* __restrict__ qq,
                            const unsigned short* __restrict__ qk,
                            float* __restrict__ q_att) {
    int w = threadIdx.x >> 6, l = threadIdx.x & 63;
    int row = blockIdx.x * 4 + w;
    uint4 av = *(const uint4*)(qq + (size_t)row * F_DIM + l * 8);
    uint4 bv = *(const uint4*)(qk + (size_t)row * F_DIM + l * 8);
    const unsigned short* ae = (const unsigned short*)&av;
    const unsigned short* be = (const unsigned short*)&bv;
    float s = 0.f;
#pragma unroll
    for (int i = 0; i < 8; ++i) s += bf2f(ae[i]) * bf2f(be[i]);
#pragma unroll
    for (int off = 32; off >= 1; off >>= 1) s += __shfl_xor(s, off);
    if (l == 0) q_att[row] = s;
}

// ---------------- flash attention, split-K partials (bf16 O_part) ----------------
// grid (S/64, NSPLIT) = 512 blocks -> 2 blocks/CU, 8 waves/CU.
__launch_bounds__(256, 2)
__global__ void flash_attn(const unsigned short* __restrict__ qq,
                           const unsigned short* __restrict__ kk,
                           const unsigned short* __restrict__ vt,  // [F][S]
                           unsigned short* __restrict__ O_part,    // [NSPLIT][S][F] bf16
                           float* __restrict__ m_part,
                           float* __restrict__ l_part) {
    __shared__ __align__(16) unsigned short Ks[32][536];   // 34.3KB, stride 268dw = 12 mod 32
    __shared__ __align__(16) unsigned short VTs[512][40];  // 40.0KB, stride 20dw: full bank partition
    __shared__ __align__(16) unsigned short Ps[4][16][32]; //  4KB, wave-private
    const float scale = 0.04415108f;  // 1/sqrt(513)
    const int tid = threadIdx.x;
    const int w = tid >> 6, l = tid & 63, quad = l >> 4, ln = l & 15;
    const int m0 = blockIdx.x * 64 + w * 16;
    const int j_begin = blockIdx.y * KSPLIT;

    // preload this wave's 16 Q rows as A-fragments
    bf16x8 aq[16];
    {
        const unsigned short* qrow = qq + (size_t)(m0 + ln) * F_DIM;
#pragma unroll
        for (int kc = 0; kc < 16; ++kc)
            aq[kc] = *(const bf16x8*)(qrow + kc * 32 + quad * 8);
    }
    f32x4 o[32];
    f32x4 zero = {0.f, 0.f, 0.f, 0.f};
#pragma unroll
    for (int i = 0; i < 32; ++i) o[i] = zero;
    float mrun[4] = {-1e30f, -1e30f, -1e30f, -1e30f};
    float lrun[4] = {0.f, 0.f, 0.f, 0.f};

    for (int jj = 0; jj < KSPLIT; jj += 32) {
        const int j0 = j_begin + jj;
        __syncthreads();  // prev iter's Ks/VTs reads complete
        // stage K rows [j0, j0+32) x 512 — coalesced uint4
#pragma unroll
        for (int it = 0; it < 8; ++it) {
            int u = it * 256 + tid;
            int r = u >> 6, c = (u & 63) * 8;
            *(uint4*)&Ks[r][c] = *(const uint4*)(kk + (size_t)(j0 + r) * F_DIM + c);
        }
        // stage V^T tile [512 f][32 j] from pre-transposed global — vector loads
#pragma unroll
        for (int it = 0; it < 8; ++it) {
            int u = it * 256 + tid;
            int f = u >> 2, jc = (u & 3) * 8;
            *(uint4*)&VTs[f][jc] = *(const uint4*)(vt + (size_t)f * S_LEN + j0 + jc);
        }
        __syncthreads();

        // S_tile = qq(16x512) @ kk_tile^T -> 16x32
        f32x4 sfr0 = zero, sfr1 = zero;
#pragma unroll
        for (int kc = 0; kc < 16; ++kc) {
            bf16x8 b0 = *(const bf16x8*)&Ks[ln][kc * 32 + quad * 8];
            bf16x8 b1 = *(const bf16x8*)&Ks[16 + ln][kc * 32 + quad * 8];
            sfr0 = __builtin_amdgcn_mfma_f32_16x16x32_bf16(aq[kc], b0, sfr0, 0, 0, 0);
            sfr1 = __builtin_amdgcn_mfma_f32_16x16x32_bf16(aq[kc], b1, sfr1, 0, 0, 0);
        }

        // online softmax (C-layout: row = quad*4+r, col = ln / 16+ln)
        float alpha[4];
#pragma unroll
        for (int r = 0; r < 4; ++r) {
            float v = fmaxf(sfr0[r], sfr1[r]);
#pragma unroll
            for (int off = 8; off >= 1; off >>= 1) v = fmaxf(v, __shfl_xor(v, off));
            float mn = fmaxf(mrun[r], v * scale);
            alpha[r] = __expf(mrun[r] - mn);
            mrun[r] = mn;
        }
        float ps0[4], ps1[4];
#pragma unroll
        for (int r = 0; r < 4; ++r) {
            ps0[r] = __expf(sfr0[r] * scale - mrun[r]);
            ps1[r] = __expf(sfr1[r] * scale - mrun[r]);
            Ps[w][quad * 4 + r][ln]      = f2bf(ps0[r]);
            Ps[w][quad * 4 + r][16 + ln] = f2bf(ps1[r]);
        }
#pragma unroll
        for (int r = 0; r < 4; ++r) {
            float v = ps0[r] + ps1[r];
#pragma unroll
            for (int off = 8; off >= 1; off >>= 1) v += __shfl_xor(v, off);
            lrun[r] = lrun[r] * alpha[r] + v;
        }
#pragma unroll
        for (int i = 0; i < 32; ++i) {
#pragma unroll
            for (int r = 0; r < 4; ++r) o[i][r] *= alpha[r];
        }

        // P C-layout -> A-layout, wave-private LDS round-trip (no barrier needed)
        __threadfence_block();
        bf16x8 pa = *(const bf16x8*)&Ps[w][ln][quad * 8];
#pragma unroll
        for (int nt = 0; nt < 32; ++nt) {
            bf16x8 b = *(const bf16x8*)&VTs[nt * 16 + ln][quad * 8];
            o[nt] = __builtin_amdgcn_mfma_f32_16x16x32_bf16(pa, b, o[nt], 0, 0, 0);
        }
    }

    unsigned short* Op = O_part + ((size_t)blockIdx.y * S_LEN + m0) * F_DIM;
#pragma unroll
    for (int nt = 0; nt < 32; ++nt) {
#pragma unroll
        for (int r = 0; r < 4; ++r)
            Op[(size_t)(quad * 4 + r) * F_DIM + nt * 16 + ln] = f2bf(o[nt][r]);
    }
    if (ln == 0) {
#pragma unroll
        for (int r = 0; r < 4; ++r) {
            m_part[(size_t)blockIdx.y * S_LEN + m0 + quad * 4 + r] = mrun[r];
            l_part[(size_t)blockIdx.y * S_LEN + m0 + quad * 4 + r] = lrun[r];
        }
    }
}

// ---------------- combine splits + q_att column + elementwise fusion ----------------
__global__ void combine_kernel(const unsigned short* __restrict__ O_part,
                               const float* __restrict__ m_part,
                               const float* __restrict__ l_part,
                               const float* __restrict__ q_att,
                               const unsigned short* __restrict__ qv,
                               unsigned short* __restrict__ res_bf) {
    const float scale = 0.04415108f;
    int row = blockIdx.x;
    int t = threadIdx.x;
    __shared__ float coef[NSPLIT];
    if (t == 0) {
        float qa_sc = q_att[row] * scale;
        float m_fin = qa_sc;
        for (int i = 0; i < NSPLIT; ++i)
            m_fin = fmaxf(m_fin, m_part[(size_t)i * S_LEN + row]);
        float l_fin = __expf(qa_sc - m_fin);  // extra column: denominator only
        float c[NSPLIT];
        for (int i = 0; i < NSPLIT; ++i) {
            c[i] = __expf(m_part[(size_t)i * S_LEN + row] - m_fin);
            l_fin += l_part[(size_t)i * S_LEN + row] * c[i];
        }
        float inv = 1.f / l_fin;
        for (int i = 0; i < NSPLIT; ++i) coef[i] = c[i] * inv;
    }
    __syncthreads();
    float qa = q_att[row];
    for (int f = t; f < F_DIM; f += blockDim.x) {
        float acc = 0.f;
#pragma unroll
        for (int i = 0; i < NSPLIT; ++i)
            acc += coef[i] * bf2f(O_part[((size_t)i * S_LEN + row) * F_DIM + f]);
        float r = bf2f(qv[(size_t)row * F_DIM + f]) * qa + acc;
        res_bf[(size_t)row * F_DIM + f] = f2bf(r);
    }
}

extern "C" void kernel_launch(void* const* d_in, const int* in_sizes, int n_in,
                              void* d_out, int out_size, void* d_ws, size_t ws_size,
                              hipStream_t stream) {
    const float* q  = (const float*)d_in[0];
    const float* k  = (const float*)d_in[1];
    const float* v  = (const float*)d_in[2];
    const float* Wq = (const float*)d_in[3];
    const float* bq = (const float*)d_in[4];
    const float* Wk = (const float*)d_in[5];
    const float* bk = (const float*)d_in[6];
    const float* Wv = (const float*)d_in[7];
    const float* bv = (const float*)d_in[8];
    const float* Wo = (const float*)d_in[9];
    const float* bo = (const float*)d_in[10];
    float* out = (float*)d_out;

    char* p = (char*)d_ws;
    auto alloc = [&](size_t bytes) -> char* {
        char* r = p; p += (bytes + 255) & ~(size_t)255; return r;
    };
    const size_t SF = (size_t)S_LEN * F_DIM;
    unsigned short* q_bf  = (unsigned short*)alloc(SF * 2);
    unsigned short* k_bf  = (unsigned short*)alloc(SF * 2);
    unsigned short* v_bf  = (unsigned short*)alloc(SF * 2);
    unsigned short* qq_bf = (unsigned short*)alloc(SF * 2);
    unsigned short* kk_bf = (unsigned short*)alloc(SF * 2);
    unsigned short* vv_bf = (unsigned short*)alloc(SF * 2);
    unsigned short* qk_bf = (unsigned short*)alloc(SF * 2);
    unsigned short* qv_bf = (unsigned short*)alloc(SF * 2);
    unsigned short* vt_bf = (unsigned short*)alloc(SF * 2);
    unsigned short* res_bf = (unsigned short*)alloc(SF * 2);
    unsigned short* wq_bf = (unsigned short*)alloc((size_t)F_DIM * F_DIM * 2);
    unsigned short* wk_bf = (unsigned short*)alloc((size_t)F_DIM * F_DIM * 2);
    unsigned short* wv_bf = (unsigned short*)alloc((size_t)F_DIM * F_DIM * 2);
    unsigned short* wo_bf = (unsigned short*)alloc((size_t)F_DIM * F_DIM * 2);
    float* q_att  = (float*)alloc((size_t)S_LEN * 4);
    float* m_part = (float*)alloc((size_t)NSPLIT * S_LEN * 4);
    float* l_part = (float*)alloc((size_t)NSPLIT * S_LEN * 4);
    unsigned short* O_part = (unsigned short*)alloc((size_t)NSPLIT * SF * 2);

    int n4 = (int)(SF / 4);
    cast_f32_bf16<<<n4 / 256, 256, 0, stream>>>(q, q_bf, n4);
    cast_f32_bf16<<<n4 / 256, 256, 0, stream>>>(k, k_bf, n4);
    cast_f32_bf16<<<n4 / 256, 256, 0, stream>>>(v, v_bf, n4);
    int w4 = F_DIM * F_DIM / 4;
    cast_f32_bf16<<<w4 / 256, 256, 0, stream>>>(Wq, wq_bf, w4);
    cast_f32_bf16<<<w4 / 256, 256, 0, stream>>>(Wk, wk_bf, w4);
    cast_f32_bf16<<<w4 / 256, 256, 0, stream>>>(Wv, wv_bf, w4);
    cast_f32_bf16<<<w4 / 256, 256, 0, stream>>>(Wo, wo_bf, w4);

    dim3 pgrid(S_LEN / 64, F_DIM / 64);
    proj_gemm<<<pgrid, 256, 0, stream>>>(q_bf, wq_bf, bq, qq_bf, nullptr, 1);
    proj_gemm<<<pgrid, 256, 0, stream>>>(k_bf, wk_bf, bk, kk_bf, nullptr, 1);
    proj_gemm<<<pgrid, 256, 0, stream>>>(v_bf, wv_bf, bv, vv_bf, nullptr, 1);
    proj_gemm<<<pgrid, 256, 0, stream>>>(q_bf, wk_bf, bk, qk_bf, nullptr, 0);
    proj_gemm<<<pgrid, 256, 0, stream>>>(q_bf, wv_bf, bv, qv_bf, nullptr, 0);

    transpose_bf16<<<dim3(S_LEN / 64, F_DIM / 64), 256, 0, stream>>>(vv_bf, vt_bf);

    qatt_kernel<<<S_LEN / 4, 256, 0, stream>>>(qq_bf, qk_bf, q_att);

    flash_attn<<<dim3(S_LEN / 64, NSPLIT), 256, 0, stream>>>(qq_bf, kk_bf, vt_bf,
                                                             O_part, m_part, l_part);

    combine_kernel<<<S_LEN, 128, 0, stream>>>(O_part, m_part, l_part, q_att, qv_bf, res_bf);

    proj_gemm<<<pgrid, 256, 0, stream>>>(res_bf, wo_bf, bo, nullptr, out, 1);
}